// Round 3
// baseline (969.118 us; speedup 1.0000x reference)
//
#include <hip/hip_runtime.h>
#include <math.h>

#define Bn 4
#define Ln 1024
#define Dn 128
#define Hn 8
#define Gn 64
#define NITERS 4

typedef _Float16 f16;
typedef _Float16 half8 __attribute__((ext_vector_type(8)));
typedef float floatx4 __attribute__((ext_vector_type(4)));

#define WPAD 136   // f16 row stride, 64/128-row row-major tiles (granule-odd: conflict-free)
#define UBPAD 72   // f16 row stride, transposed 128x64 tiles
#define PBPAD 72   // f16 row stride, P tile

#define MFMA(a, b, c) __builtin_amdgcn_mfma_f32_16x16x32_f16((a), (b), (c), 0, 0, 0)

// ---------------- repack ternary/global into f16 per-head layouts -----------
__global__ void repack_kernel(const float* __restrict__ ter, const float* __restrict__ glb,
                              f16* __restrict__ TpA, f16* __restrict__ TpB,
                              f16* __restrict__ GpA, f16* __restrict__ Gpt) {
    int idx = blockIdx.x * 256 + threadIdx.x;
    if (idx < Dn * Dn * Hn) {
        int h = idx % Hn; int b = (idx / Hn) % Dn; int a = idx / (Hn * Dn);
        f16 v = (f16)ter[idx];
        TpA[((size_t)h * Dn + a) * Dn + b] = v;
        TpB[((size_t)h * Dn + b) * Dn + a] = v;
    }
    if (idx < Gn * Dn * Hn) {
        int h = idx % Hn; int a = (idx / Hn) % Dn; int g = idx / (Hn * Dn);
        f16 v = (f16)glb[idx];
        GpA[((size_t)h * Gn + g) * Dn + a] = v;
        Gpt[((size_t)h * Dn + a) * Gn + g] = v;
    }
}

// ---------------- row softmax over D=128 (fp32 in, f16 out) -----------------
__global__ void softmax_rows_kernel(const float* __restrict__ in, f16* __restrict__ out) {
    int row = blockIdx.x;
    int t = threadIdx.x;  // 0..127
    __shared__ float red[2];
    float v = in[(size_t)row * Dn + t];
    float m = v;
    #pragma unroll
    for (int off = 1; off < 64; off <<= 1) m = fmaxf(m, __shfl_xor(m, off, 64));
    if ((t & 63) == 0) red[t >> 6] = m;
    __syncthreads();
    m = fmaxf(red[0], red[1]);
    float e = __expf(v - m);
    float s = e;
    #pragma unroll
    for (int off = 1; off < 64; off <<= 1) s += __shfl_xor(s, off, 64);
    __syncthreads();
    if ((t & 63) == 0) red[t >> 6] = s;
    __syncthreads();
    s = red[0] + red[1];
    out[(size_t)row * Dn + t] = (f16)(e / s);
}

// ---------------- U/V projection via MFMA -----------------------------------
__launch_bounds__(256, 4)
__global__ void uv_kernel(const f16* __restrict__ Qz, const f16* __restrict__ TpA,
                          const f16* __restrict__ TpB,
                          f16* __restrict__ U, f16* __restrict__ Ut, f16* __restrict__ Vt) {
    int bx = blockIdx.x;  // 16 j-strips of 64
    int h  = blockIdx.y;
    int n  = blockIdx.z;
    int t  = threadIdx.x;
    int w = t >> 6, l = t & 63, m = l & 15, q = l >> 4;

    __shared__ __align__(16) f16 Ts[128 * WPAD];

    int jrow = bx * 64 + w * 16 + m;
    const f16* qbase = Qz + ((size_t)n * Ln + jrow) * Dn;
    half8 aq[4];
    #pragma unroll
    for (int ks = 0; ks < 4; ks++)
        aq[ks] = *(const half8*)(qbase + ks * 32 + q * 8);

    size_t hoff = (size_t)(n * Hn + h);
    int jr0 = bx * 64 + w * 16 + 4 * q;
    typedef _Float16 half4v __attribute__((ext_vector_type(4)));

    // ---- pass 1: U = Qz * TpA^T ----
    {
        const f16* src = TpA + (size_t)h * Dn * Dn;
        for (int ii = 0; ii < 8; ii++) {
            int idx = t + 256 * ii; int r = idx >> 4, c = idx & 15;
            *(float4*)&Ts[r * WPAD + c * 8] = *(const float4*)(src + (size_t)r * Dn + c * 8);
        }
        __syncthreads();
        #pragma unroll
        for (int ct = 0; ct < 8; ct++) {
            floatx4 acc = {0.f, 0.f, 0.f, 0.f};
            #pragma unroll
            for (int ks = 0; ks < 4; ks++) {
                half8 b = *(const half8*)&Ts[(ct * 16 + m) * WPAD + ks * 32 + q * 8];
                acc = MFMA(aq[ks], b, acc);
            }
            f16* ub = U + (hoff * Ln + jr0) * Dn + ct * 16 + m;
            #pragma unroll
            for (int reg = 0; reg < 4; reg++) ub[(size_t)reg * Dn] = (f16)acc[reg];
            half4v pk = { (f16)acc[0], (f16)acc[1], (f16)acc[2], (f16)acc[3] };
            *(half4v*)(Ut + (hoff * Dn + ct * 16 + m) * Ln + jr0) = pk;
        }
        __syncthreads();
    }
    // ---- pass 2: V = Qz * TpB^T, stored transposed ----
    {
        const f16* src = TpB + (size_t)h * Dn * Dn;
        for (int ii = 0; ii < 8; ii++) {
            int idx = t + 256 * ii; int r = idx >> 4, c = idx & 15;
            *(float4*)&Ts[r * WPAD + c * 8] = *(const float4*)(src + (size_t)r * Dn + c * 8);
        }
        __syncthreads();
        #pragma unroll
        for (int ct = 0; ct < 8; ct++) {
            floatx4 acc = {0.f, 0.f, 0.f, 0.f};
            #pragma unroll
            for (int ks = 0; ks < 4; ks++) {
                half8 b = *(const half8*)&Ts[(ct * 16 + m) * WPAD + ks * 32 + q * 8];
                acc = MFMA(aq[ks], b, acc);
            }
            half4v pk = { (f16)acc[0], (f16)acc[1], (f16)acc[2], (f16)acc[3] };
            *(half4v*)(Vt + (hoff * Dn + ct * 16 + m) * Ln + jr0) = pk;
        }
    }
}

// ---------------- msg_i + msg_g: no-max flash, fragment-reuse tiling --------
__launch_bounds__(256, 2)
__global__ void msgi_kernel(const f16* __restrict__ Qz, const f16* __restrict__ U,
                            const f16* __restrict__ Ut, const f16* __restrict__ GpA,
                            const f16* __restrict__ Gpt, const int* __restrict__ mask,
                            f16* __restrict__ Macc, float* __restrict__ rowL) {
    int it = blockIdx.x, h = blockIdx.y, n = blockIdx.z;
    int t = threadIdx.x;
    int w = t >> 6, l = t & 63, m = l & 15, q = l >> 4;

    __shared__ __align__(16) f16 Us[64 * WPAD];
    __shared__ __align__(16) f16 Ub[128 * UBPAD];
    __shared__ __align__(16) f16 Pb[64 * PBPAD];
    __shared__ float lredW[4][64];
    __shared__ float linvS[64];

    // stage Qz tile into Us, preload 16 A-fragments (wave covers all 64 rows)
    {
        const f16* src = Qz + ((size_t)n * Ln + it * 64) * Dn;
        for (int ii = 0; ii < 4; ii++) {
            int idx = t + 256 * ii; int r = idx >> 4, c = idx & 15;
            *(float4*)&Us[r * WPAD + c * 8] = *(const float4*)(src + (size_t)r * Dn + c * 8);
        }
    }
    __syncthreads();
    half8 aq[4][4];
    #pragma unroll
    for (int rb = 0; rb < 4; rb++)
        #pragma unroll
        for (int ks = 0; ks < 4; ks++)
            aq[rb][ks] = *(const half8*)&Us[(rb * 16 + m) * WPAD + ks * 32 + q * 8];
    int im[4][4];
    #pragma unroll
    for (int rb = 0; rb < 4; rb++)
        #pragma unroll
        for (int reg = 0; reg < 4; reg++)
            im[rb][reg] = mask[n * Ln + it * 64 + rb * 16 + 4 * q + reg];
    __syncthreads();

    float lacc[4][4];
    floatx4 Oacc[4][2];
    #pragma unroll
    for (int rb = 0; rb < 4; rb++) {
        #pragma unroll
        for (int reg = 0; reg < 4; reg++) lacc[rb][reg] = 0.f;
        Oacc[rb][0] = (floatx4){0.f, 0.f, 0.f, 0.f};
        Oacc[rb][1] = (floatx4){0.f, 0.f, 0.f, 0.f};
    }

    size_t hoff = (size_t)(n * Hn + h);

    // prefetch jt=0 tiles into registers
    float4 pUs[4], pUb[4];
    {
        const f16* usrc = U + hoff * Ln * Dn;
        const f16* ubsrc = Ut + hoff * Dn * Ln;
        #pragma unroll
        for (int ii = 0; ii < 4; ii++) {
            int idx = t + 256 * ii;
            pUs[ii] = *(const float4*)(usrc + (size_t)(idx >> 4) * Dn + (idx & 15) * 8);
            pUb[ii] = *(const float4*)(ubsrc + (size_t)(idx >> 3) * Ln + (idx & 7) * 8);
        }
    }
    int jvcur = mask[n * Ln + 16 * w + m];

    for (int jt = 0; jt < 17; jt++) {
        // commit staged tiles
        #pragma unroll
        for (int ii = 0; ii < 4; ii++) {
            int idx = t + 256 * ii;
            *(float4*)&Us[(idx >> 4) * WPAD + (idx & 15) * 8] = pUs[ii];
            *(float4*)&Ub[(idx >> 3) * UBPAD + (idx & 7) * 8] = pUb[ii];
        }
        __syncthreads();
        int jv = jvcur;
        // prefetch next tile
        if (jt < 16) {
            const f16* usrc; const f16* ubsrc; size_t ubstride;
            if (jt + 1 < 16) {
                usrc = U + (hoff * Ln + (jt + 1) * 64) * Dn;
                ubsrc = Ut + hoff * Dn * Ln + (jt + 1) * 64;
                ubstride = Ln;
            } else {
                usrc = GpA + (size_t)h * Gn * Dn;
                ubsrc = Gpt + (size_t)h * Dn * Gn;
                ubstride = Gn;
            }
            #pragma unroll
            for (int ii = 0; ii < 4; ii++) {
                int idx = t + 256 * ii;
                pUs[ii] = *(const float4*)(usrc + (size_t)(idx >> 4) * Dn + (idx & 15) * 8);
                pUb[ii] = *(const float4*)(ubsrc + (size_t)(idx >> 3) * ubstride + (idx & 7) * 8);
            }
            jvcur = (jt + 1 < 16) ? mask[n * Ln + (jt + 1) * 64 + 16 * w + m] : 1;
        }
        // scores: B-frags read once per ks, reused across 4 row-blocks
        half8 bU[4];
        #pragma unroll
        for (int ks = 0; ks < 4; ks++)
            bU[ks] = *(const half8*)&Us[(16 * w + m) * WPAD + ks * 32 + q * 8];
        floatx4 s[4];
        #pragma unroll
        for (int rb = 0; rb < 4; rb++) {
            floatx4 acc = {0.f, 0.f, 0.f, 0.f};
            #pragma unroll
            for (int ks = 0; ks < 4; ks++) acc = MFMA(aq[rb][ks], bU[ks], acc);
            s[rb] = acc;
        }
        bool isg = (jt == 16);
        #pragma unroll
        for (int rb = 0; rb < 4; rb++)
            #pragma unroll
            for (int reg = 0; reg < 4; reg++) {
                float sv = fminf(s[rb][reg], 11.f);
                float p = (isg || (im[rb][reg] && jv)) ? __expf(sv) : 0.f;
                lacc[rb][reg] += p;
                Pb[(rb * 16 + 4 * q + reg) * PBPAD + 16 * w + m] = (f16)p;
            }
        __syncthreads();
        // PV: wave = 4 row-blocks x 2 col-blocks (cols 32w..32w+31)
        #pragma unroll
        for (int ks2 = 0; ks2 < 2; ks2++) {
            half8 aP[4], bUt[2];
            #pragma unroll
            for (int rb = 0; rb < 4; rb++)
                aP[rb] = *(const half8*)&Pb[(rb * 16 + m) * PBPAD + ks2 * 32 + q * 8];
            #pragma unroll
            for (int cb = 0; cb < 2; cb++)
                bUt[cb] = *(const half8*)&Ub[(32 * w + cb * 16 + m) * UBPAD + ks2 * 32 + q * 8];
            #pragma unroll
            for (int rb = 0; rb < 4; rb++)
                #pragma unroll
                for (int cb = 0; cb < 2; cb++)
                    Oacc[rb][cb] = MFMA(aP[rb], bUt[cb], Oacc[rb][cb]);
        }
        __syncthreads();
    }

    // reduce row sums over the 16 m-lanes, then across waves
    #pragma unroll
    for (int rb = 0; rb < 4; rb++)
        #pragma unroll
        for (int reg = 0; reg < 4; reg++) {
            float v = lacc[rb][reg];
            #pragma unroll
            for (int off = 1; off < 16; off <<= 1) v += __shfl_xor(v, off, 64);
            lacc[rb][reg] = v;
        }
    if (m == 0)
        #pragma unroll
        for (int rb = 0; rb < 4; rb++)
            #pragma unroll
            for (int reg = 0; reg < 4; reg++)
                lredW[w][rb * 16 + 4 * q + reg] = lacc[rb][reg];
    __syncthreads();
    size_t rbase = hoff * Ln + it * 64;
    if (t < 64) {
        float s4 = lredW[0][t] + lredW[1][t] + lredW[2][t] + lredW[3][t];
        rowL[rbase + t] = s4;
        linvS[t] = 1.0f / s4;
    }
    __syncthreads();
    f16* Mo = Macc + rbase * Dn;
    #pragma unroll
    for (int rb = 0; rb < 4; rb++)
        #pragma unroll
        for (int reg = 0; reg < 4; reg++) {
            int row = rb * 16 + 4 * q + reg;
            float inv = linvS[row];
            #pragma unroll
            for (int cb = 0; cb < 2; cb++)
                Mo[(size_t)row * Dn + 32 * w + cb * 16 + m] = (f16)(Oacc[rb][cb][reg] * inv);
        }
}

// ---------------- msg_j: P^T * V using stored row sums ----------------------
__launch_bounds__(256, 2)
__global__ void msgj_kernel(const f16* __restrict__ Qz, const f16* __restrict__ U,
                            const f16* __restrict__ Vt, const int* __restrict__ mask,
                            const float* __restrict__ rowL, f16* __restrict__ Macc) {
    int jt = blockIdx.x, h = blockIdx.y, n = blockIdx.z;
    int t = threadIdx.x;
    int w = t >> 6, l = t & 63, m = l & 15, q = l >> 4;

    __shared__ __align__(16) f16 Qs[64 * WPAD];
    __shared__ __align__(16) f16 Vb[128 * UBPAD];
    __shared__ __align__(16) f16 Pb[64 * PBPAD];

    size_t hoff = (size_t)(n * Hn + h);

    // stage U j-tile into Qs, preload 16 A-fragments + j-mask regs
    {
        const f16* src = U + (hoff * Ln + jt * 64) * Dn;
        for (int ii = 0; ii < 4; ii++) {
            int idx = t + 256 * ii; int r = idx >> 4, c = idx & 15;
            *(float4*)&Qs[r * WPAD + c * 8] = *(const float4*)(src + (size_t)r * Dn + c * 8);
        }
    }
    __syncthreads();
    half8 au[4][4];
    #pragma unroll
    for (int rb = 0; rb < 4; rb++)
        #pragma unroll
        for (int ks = 0; ks < 4; ks++)
            au[rb][ks] = *(const half8*)&Qs[(rb * 16 + m) * WPAD + ks * 32 + q * 8];
    int jm[4][4];
    #pragma unroll
    for (int rb = 0; rb < 4; rb++)
        #pragma unroll
        for (int reg = 0; reg < 4; reg++)
            jm[rb][reg] = mask[n * Ln + jt * 64 + rb * 16 + 4 * q + reg];
    __syncthreads();

    floatx4 Oacc[4][2];
    #pragma unroll
    for (int rb = 0; rb < 4; rb++) {
        Oacc[rb][0] = (floatx4){0.f, 0.f, 0.f, 0.f};
        Oacc[rb][1] = (floatx4){0.f, 0.f, 0.f, 0.f};
    }

    float4 pQ[4], pV[4];
    {
        const f16* qsrc = Qz + (size_t)n * Ln * Dn;
        const f16* vsrc = Vt + hoff * Dn * Ln;
        #pragma unroll
        for (int ii = 0; ii < 4; ii++) {
            int idx = t + 256 * ii;
            pQ[ii] = *(const float4*)(qsrc + (size_t)(idx >> 4) * Dn + (idx & 15) * 8);
            pV[ii] = *(const float4*)(vsrc + (size_t)(idx >> 3) * Ln + (idx & 7) * 8);
        }
    }
    int ivcur = mask[n * Ln + 16 * w + m];
    float lcur = rowL[hoff * Ln + 16 * w + m];

    for (int it2 = 0; it2 < 16; it2++) {
        #pragma unroll
        for (int ii = 0; ii < 4; ii++) {
            int idx = t + 256 * ii;
            *(float4*)&Qs[(idx >> 4) * WPAD + (idx & 15) * 8] = pQ[ii];
            *(float4*)&Vb[(idx >> 3) * UBPAD + (idx & 7) * 8] = pV[ii];
        }
        __syncthreads();
        int iv = ivcur;
        float linv = 1.0f / lcur;
        if (it2 < 15) {
            const f16* qsrc = Qz + ((size_t)n * Ln + (it2 + 1) * 64) * Dn;
            const f16* vsrc = Vt + hoff * Dn * Ln + (it2 + 1) * 64;
            #pragma unroll
            for (int ii = 0; ii < 4; ii++) {
                int idx = t + 256 * ii;
                pQ[ii] = *(const float4*)(qsrc + (size_t)(idx >> 4) * Dn + (idx & 15) * 8);
                pV[ii] = *(const float4*)(vsrc + (size_t)(idx >> 3) * Ln + (idx & 7) * 8);
            }
            ivcur = mask[n * Ln + (it2 + 1) * 64 + 16 * w + m];
            lcur = rowL[hoff * Ln + (it2 + 1) * 64 + 16 * w + m];
        }
        // S^T scores: rows j, cols i (wave's 16 i-cols), B-frags reused
        half8 bQ[4];
        #pragma unroll
        for (int ks = 0; ks < 4; ks++)
            bQ[ks] = *(const half8*)&Qs[(16 * w + m) * WPAD + ks * 32 + q * 8];
        #pragma unroll
        for (int rb = 0; rb < 4; rb++) {
            floatx4 acc = {0.f, 0.f, 0.f, 0.f};
            #pragma unroll
            for (int ks = 0; ks < 4; ks++) acc = MFMA(au[rb][ks], bQ[ks], acc);
            #pragma unroll
            for (int reg = 0; reg < 4; reg++) {
                float sv = fminf(acc[reg], 11.f);
                float p = (iv && jm[rb][reg]) ? __expf(sv) * linv : 0.f;
                Pb[(rb * 16 + 4 * q + reg) * PBPAD + 16 * w + m] = (f16)p;
            }
        }
        __syncthreads();
        #pragma unroll
        for (int ks2 = 0; ks2 < 2; ks2++) {
            half8 aP[4], bV[2];
            #pragma unroll
            for (int rb = 0; rb < 4; rb++)
                aP[rb] = *(const half8*)&Pb[(rb * 16 + m) * PBPAD + ks2 * 32 + q * 8];
            #pragma unroll
            for (int cb = 0; cb < 2; cb++)
                bV[cb] = *(const half8*)&Vb[(32 * w + cb * 16 + m) * UBPAD + ks2 * 32 + q * 8];
            #pragma unroll
            for (int rb = 0; rb < 4; rb++)
                #pragma unroll
                for (int cb = 0; cb < 2; cb++)
                    Oacc[rb][cb] = MFMA(aP[rb], bV[cb], Oacc[rb][cb]);
        }
        __syncthreads();
    }

    f16* Mo = Macc + (hoff * Ln + jt * 64) * Dn;
    #pragma unroll
    for (int rb = 0; rb < 4; rb++)
        #pragma unroll
        for (int reg = 0; reg < 4; reg++) {
            int row = rb * 16 + 4 * q + reg;
            #pragma unroll
            for (int cb = 0; cb < 2; cb++) {
                f16* p = &Mo[(size_t)row * Dn + 32 * w + cb * 16 + m];
                *p = (f16)((float)*p + Oacc[rb][cb][reg]);
            }
        }
}

// ---------------- fused combine (+softmax | +mask) --------------------------
__global__ void combine_kernel(const float* __restrict__ x, const f16* __restrict__ Macc,
                               const int* __restrict__ mask, float* __restrict__ out,
                               f16* __restrict__ Qzh, int do_softmax, int do_mask) {
    int row = blockIdx.x;           // B*L rows
    int t = threadIdx.x;            // 0..127
    __shared__ float red[2];
    int n = row >> 10;
    float acc = x[(size_t)row * Dn + t];
    const f16* mp = Macc + (size_t)n * Hn * Ln * Dn + (size_t)(row & 1023) * Dn + t;
    #pragma unroll
    for (int h = 0; h < Hn; h++) acc += (float)mp[(size_t)h * Ln * Dn];
    float o = acc;
    if (do_mask && mask[row] == 0) o = 0.f;
    out[(size_t)row * Dn + t] = o;
    if (do_softmax) {
        float m = acc;
        #pragma unroll
        for (int off = 1; off < 64; off <<= 1) m = fmaxf(m, __shfl_xor(m, off, 64));
        if ((t & 63) == 0) red[t >> 6] = m;
        __syncthreads();
        m = fmaxf(red[0], red[1]);
        float e = __expf(acc - m);
        float s = e;
        #pragma unroll
        for (int off = 1; off < 64; off <<= 1) s += __shfl_xor(s, off, 64);
        __syncthreads();
        if ((t & 63) == 0) red[t >> 6] = s;
        __syncthreads();
        s = red[0] + red[1];
        Qzh[(size_t)row * Dn + t] = (f16)(e / s);
    }
}

extern "C" void kernel_launch(void* const* d_in, const int* in_sizes, int n_in,
                              void* d_out, int out_size, void* d_ws, size_t ws_size,
                              hipStream_t stream) {
    const float* x       = (const float*)d_in[0];
    const int*   mask    = (const int*)d_in[1];
    const float* ternary = (const float*)d_in[2];
    const float* global_ = (const float*)d_in[3];
    float* out = (float*)d_out;
    (void)ws_size; (void)n_in; (void)in_sizes; (void)out_size;

    char* ws = (char*)d_ws;
    size_t o = 0;
    f16* Qzh = (f16*)(ws + o); o += (size_t)Bn * Ln * Dn * 2;
    f16* U   = (f16*)(ws + o); o += (size_t)Bn * Hn * Ln * Dn * 2;
    f16* Ut  = (f16*)(ws + o); o += (size_t)Bn * Hn * Ln * Dn * 2;
    f16* Vt  = (f16*)(ws + o); o += (size_t)Bn * Hn * Ln * Dn * 2;
    f16* TpA = (f16*)(ws + o); o += (size_t)Hn * Dn * Dn * 2;
    f16* TpB = (f16*)(ws + o); o += (size_t)Hn * Dn * Dn * 2;
    f16* GpA = (f16*)(ws + o); o += (size_t)Hn * Gn * Dn * 2;
    f16* Gpt = (f16*)(ws + o); o += (size_t)Hn * Dn * Gn * 2;
    float* rowL = (float*)(ws + o); o += (size_t)Bn * Hn * Ln * 4;
    f16* Macc = (f16*)(ws + o); o += (size_t)Bn * Hn * Ln * Dn * 2;

    repack_kernel<<<(Dn * Dn * Hn + 255) / 256, 256, 0, stream>>>(ternary, global_, TpA, TpB, GpA, Gpt);
    softmax_rows_kernel<<<Bn * Ln, 128, 0, stream>>>(x, Qzh);

    for (int it = 0; it < NITERS; it++) {
        uv_kernel<<<dim3(Ln / 64, Hn, Bn), 256, 0, stream>>>(Qzh, TpA, TpB, U, Ut, Vt);
        msgi_kernel<<<dim3(Ln / 64, Hn, Bn), 256, 0, stream>>>(Qzh, U, Ut, GpA, Gpt, mask, Macc, rowL);
        msgj_kernel<<<dim3(Ln / 64, Hn, Bn), 256, 0, stream>>>(Qzh, U, Vt, mask, rowL, Macc);
        combine_kernel<<<Bn * Ln, 128, 0, stream>>>(x, Macc, mask, out, Qzh,
                                                    (it < NITERS - 1) ? 1 : 0,
                                                    (it == NITERS - 1) ? 1 : 0);
    }
}

// Round 4
// 877.463 us; speedup vs baseline: 1.1045x; 1.1045x over previous
//
#include <hip/hip_runtime.h>
#include <math.h>

#define Bn 4
#define Ln 1024
#define Dn 128
#define Hn 8
#define Gn 64
#define NITERS 4

typedef _Float16 f16;
typedef _Float16 half8 __attribute__((ext_vector_type(8)));
typedef _Float16 half4v __attribute__((ext_vector_type(4)));
typedef float floatx4 __attribute__((ext_vector_type(4)));

#define WPAD 136   // f16 row stride, 128-col row-major tiles; (m+q)%8 balanced bank groups
#define UBPAD 72   // f16 row stride, transposed 128x64 tiles
#define PBPAD 72   // f16 row stride, wave-private P strips

#define MFMA(a, b, c) __builtin_amdgcn_mfma_f32_16x16x32_f16((a), (b), (c), 0, 0, 0)

// ---------------- repack ternary/global into f16 per-head layouts -----------
__global__ void repack_kernel(const float* __restrict__ ter, const float* __restrict__ glb,
                              f16* __restrict__ TpA, f16* __restrict__ TpB,
                              f16* __restrict__ GpA, f16* __restrict__ Gpt) {
    int idx = blockIdx.x * 256 + threadIdx.x;
    if (idx < Dn * Dn * Hn) {
        int h = idx % Hn; int b = (idx / Hn) % Dn; int a = idx / (Hn * Dn);
        f16 v = (f16)ter[idx];
        TpA[((size_t)h * Dn + a) * Dn + b] = v;
        TpB[((size_t)h * Dn + b) * Dn + a] = v;
    }
    if (idx < Gn * Dn * Hn) {
        int h = idx % Hn; int a = (idx / Hn) % Dn; int g = idx / (Hn * Dn);
        f16 v = (f16)glb[idx];
        GpA[((size_t)h * Gn + g) * Dn + a] = v;
        Gpt[((size_t)h * Dn + a) * Gn + g] = v;
    }
}

// ---------------- row softmax over D=128 (fp32 in, f16 out) -----------------
__global__ void softmax_rows_kernel(const float* __restrict__ in, f16* __restrict__ out) {
    int row = blockIdx.x;
    int t = threadIdx.x;  // 0..127
    __shared__ float red[2];
    float v = in[(size_t)row * Dn + t];
    float m = v;
    #pragma unroll
    for (int off = 1; off < 64; off <<= 1) m = fmaxf(m, __shfl_xor(m, off, 64));
    if ((t & 63) == 0) red[t >> 6] = m;
    __syncthreads();
    m = fmaxf(red[0], red[1]);
    float e = __expf(v - m);
    float s = e;
    #pragma unroll
    for (int off = 1; off < 64; off <<= 1) s += __shfl_xor(s, off, 64);
    __syncthreads();
    if ((t & 63) == 0) red[t >> 6] = s;
    __syncthreads();
    s = red[0] + red[1];
    out[(size_t)row * Dn + t] = (f16)(e / s);
}

// ---------------- U/V projection via MFMA -----------------------------------
__launch_bounds__(256, 4)
__global__ void uv_kernel(const f16* __restrict__ Qz, const f16* __restrict__ TpA,
                          const f16* __restrict__ TpB,
                          f16* __restrict__ U, f16* __restrict__ Ut, f16* __restrict__ Vt) {
    int bx = blockIdx.x;  // 16 j-strips of 64
    int h  = blockIdx.y;
    int n  = blockIdx.z;
    int t  = threadIdx.x;
    int w = t >> 6, l = t & 63, m = l & 15, q = l >> 4;

    __shared__ __align__(16) f16 Ts[128 * WPAD];

    int jrow = bx * 64 + w * 16 + m;
    const f16* qbase = Qz + ((size_t)n * Ln + jrow) * Dn;
    half8 aq[4];
    #pragma unroll
    for (int ks = 0; ks < 4; ks++)
        aq[ks] = *(const half8*)(qbase + ks * 32 + q * 8);

    size_t hoff = (size_t)(n * Hn + h);
    int jr0 = bx * 64 + w * 16 + 4 * q;

    // ---- pass 1: U = Qz * TpA^T ----
    {
        const f16* src = TpA + (size_t)h * Dn * Dn;
        for (int ii = 0; ii < 8; ii++) {
            int idx = t + 256 * ii; int r = idx >> 4, c = idx & 15;
            *(float4*)&Ts[r * WPAD + c * 8] = *(const float4*)(src + (size_t)r * Dn + c * 8);
        }
        __syncthreads();
        #pragma unroll
        for (int ct = 0; ct < 8; ct++) {
            floatx4 acc = {0.f, 0.f, 0.f, 0.f};
            #pragma unroll
            for (int ks = 0; ks < 4; ks++) {
                half8 b = *(const half8*)&Ts[(ct * 16 + m) * WPAD + ks * 32 + q * 8];
                acc = MFMA(aq[ks], b, acc);
            }
            f16* ub = U + (hoff * Ln + jr0) * Dn + ct * 16 + m;
            #pragma unroll
            for (int reg = 0; reg < 4; reg++) ub[(size_t)reg * Dn] = (f16)acc[reg];
            half4v pk = { (f16)acc[0], (f16)acc[1], (f16)acc[2], (f16)acc[3] };
            *(half4v*)(Ut + (hoff * Dn + ct * 16 + m) * Ln + jr0) = pk;
        }
        __syncthreads();
    }
    // ---- pass 2: V = Qz * TpB^T, stored transposed ----
    {
        const f16* src = TpB + (size_t)h * Dn * Dn;
        for (int ii = 0; ii < 8; ii++) {
            int idx = t + 256 * ii; int r = idx >> 4, c = idx & 15;
            *(float4*)&Ts[r * WPAD + c * 8] = *(const float4*)(src + (size_t)r * Dn + c * 8);
        }
        __syncthreads();
        #pragma unroll
        for (int ct = 0; ct < 8; ct++) {
            floatx4 acc = {0.f, 0.f, 0.f, 0.f};
            #pragma unroll
            for (int ks = 0; ks < 4; ks++) {
                half8 b = *(const half8*)&Ts[(ct * 16 + m) * WPAD + ks * 32 + q * 8];
                acc = MFMA(aq[ks], b, acc);
            }
            half4v pk = { (f16)acc[0], (f16)acc[1], (f16)acc[2], (f16)acc[3] };
            *(half4v*)(Vt + (hoff * Dn + ct * 16 + m) * Ln + jr0) = pk;
        }
    }
}

// ---------------- msg_i + msg_g: no-max flash, R2 wave-strip tiling ---------
// Wave w owns i-rows [16w,16w+16); P strip is wave-private (no barrier between
// P write and PV read). 2 barriers per jt. Register prefetch of next tiles.
__launch_bounds__(256, 2)
__global__ void msgi_kernel(const f16* __restrict__ Qz, const f16* __restrict__ U,
                            const f16* __restrict__ Ut, const f16* __restrict__ GpA,
                            const f16* __restrict__ Gpt, const int* __restrict__ mask,
                            f16* __restrict__ Macc, float* __restrict__ rowLinv) {
    int it = blockIdx.x, h = blockIdx.y, n = blockIdx.z;
    int t = threadIdx.x;
    int w = t >> 6, l = t & 63, m = l & 15, q = l >> 4;

    __shared__ __align__(16) f16 Us[64 * WPAD];
    __shared__ __align__(16) f16 Ub[128 * UBPAD];
    __shared__ __align__(16) f16 Pb[64 * PBPAD];

    // stage Qz tile, read jt-invariant A-fragments (16 VGPRs)
    {
        const f16* src = Qz + ((size_t)n * Ln + it * 64) * Dn;
        #pragma unroll
        for (int ii = 0; ii < 4; ii++) {
            int idx = t + 256 * ii; int r = idx >> 4, c = idx & 15;
            *(float4*)&Us[r * WPAD + c * 8] = *(const float4*)(src + (size_t)r * Dn + c * 8);
        }
    }
    __syncthreads();
    half8 aq[4];
    #pragma unroll
    for (int ks = 0; ks < 4; ks++)
        aq[ks] = *(const half8*)&Us[(w * 16 + m) * WPAD + ks * 32 + q * 8];
    int im[4];
    #pragma unroll
    for (int reg = 0; reg < 4; reg++)
        im[reg] = mask[n * Ln + it * 64 + w * 16 + 4 * q + reg];

    size_t hoff = (size_t)(n * Hn + h);
    // prefetch jt=0 tiles into registers (32 VGPRs)
    float4 pUs[4], pUb[4];
    {
        const f16* us = U + hoff * Ln * Dn;
        const f16* ub = Ut + hoff * Dn * Ln;
        #pragma unroll
        for (int ii = 0; ii < 4; ii++) {
            int idx = t + 256 * ii;
            pUs[ii] = *(const float4*)(us + (size_t)(idx >> 4) * Dn + (idx & 15) * 8);
            pUb[ii] = *(const float4*)(ub + (size_t)(idx >> 3) * Ln + (idx & 7) * 8);
        }
    }
    __syncthreads();  // aq reads complete before Us is overwritten

    float lacc[4] = {0.f, 0.f, 0.f, 0.f};
    floatx4 Oacc[8];
    #pragma unroll
    for (int c = 0; c < 8; c++) Oacc[c] = (floatx4){0.f, 0.f, 0.f, 0.f};
    f16* Pw = &Pb[w * 16 * PBPAD];

    for (int jt = 0; jt < 17; jt++) {
        // commit prefetched tiles
        #pragma unroll
        for (int ii = 0; ii < 4; ii++) {
            int idx = t + 256 * ii;
            *(float4*)&Us[(idx >> 4) * WPAD + (idx & 15) * 8] = pUs[ii];
            *(float4*)&Ub[(idx >> 3) * UBPAD + (idx & 7) * 8] = pUb[ii];
        }
        __syncthreads();
        bool isg = (jt == 16);
        int jmv[4];
        #pragma unroll
        for (int ct = 0; ct < 4; ct++)
            jmv[ct] = isg ? 1 : mask[n * Ln + jt * 64 + ct * 16 + m];
        // prefetch next tiles (loads in flight across the compute below)
        if (jt < 16) {
            const f16 *us, *ub; size_t ustr;
            if (jt + 1 < 16) {
                us = U + (hoff * Ln + (jt + 1) * 64) * Dn;
                ub = Ut + hoff * Dn * Ln + (jt + 1) * 64;
                ustr = Ln;
            } else {
                us = GpA + (size_t)h * Gn * Dn;
                ub = Gpt + (size_t)h * Dn * Gn;
                ustr = Gn;
            }
            #pragma unroll
            for (int ii = 0; ii < 4; ii++) {
                int idx = t + 256 * ii;
                pUs[ii] = *(const float4*)(us + (size_t)(idx >> 4) * Dn + (idx & 15) * 8);
                pUb[ii] = *(const float4*)(ub + (size_t)(idx >> 3) * ustr + (idx & 7) * 8);
            }
        }
        // scores: S[i = 16w+4q+reg][j = ct*16+m], p = exp(s) (no max), P -> strip
        #pragma unroll
        for (int ct = 0; ct < 4; ct++) {
            floatx4 s = {0.f, 0.f, 0.f, 0.f};
            #pragma unroll
            for (int ks = 0; ks < 4; ks++) {
                half8 b = *(const half8*)&Us[(ct * 16 + m) * WPAD + ks * 32 + q * 8];
                s = MFMA(aq[ks], b, s);
            }
            #pragma unroll
            for (int reg = 0; reg < 4; reg++) {
                float sv = __expf(fminf(s[reg], 11.f));
                float p = (isg || (im[reg] && jmv[ct])) ? sv : 0.f;
                lacc[reg] += p;
                Pw[(4 * q + reg) * PBPAD + ct * 16 + m] = (f16)p;
            }
        }
        // PV: O[strip rows][128 cols] += P * U_tile  (wave-private P)
        #pragma unroll
        for (int ks2 = 0; ks2 < 2; ks2++) {
            half8 aP = *(const half8*)&Pw[m * PBPAD + ks2 * 32 + q * 8];
            #pragma unroll
            for (int c = 0; c < 8; c++) {
                half8 bU = *(const half8*)&Ub[(c * 16 + m) * UBPAD + ks2 * 32 + q * 8];
                Oacc[c] = MFMA(aP, bU, Oacc[c]);
            }
        }
        __syncthreads();
    }

    // epilogue: reduce row sums over 16 m-lanes (rows live in-wave)
    float inv[4];
    #pragma unroll
    for (int reg = 0; reg < 4; reg++) {
        float v = lacc[reg];
        #pragma unroll
        for (int off = 1; off < 16; off <<= 1) v += __shfl_xor(v, off, 64);
        inv[reg] = 1.0f / v;
    }
    size_t rbase = hoff * Ln + (size_t)it * 64 + w * 16 + 4 * q;
    if (m == 0) {
        #pragma unroll
        for (int reg = 0; reg < 4; reg++)
            rowLinv[rbase + reg] = im[reg] ? inv[reg] : 0.f;  // mask folded for msgj
    }
    f16* Mo = Macc + rbase * Dn;
    #pragma unroll
    for (int reg = 0; reg < 4; reg++)
        #pragma unroll
        for (int c = 0; c < 8; c++)
            Mo[(size_t)reg * Dn + c * 16 + m] = (f16)(Oacc[c][reg] * inv[reg]);
}

// ---------------- msg_j: P^T * V using premultiplied rowLinv ----------------
__launch_bounds__(256, 2)
__global__ void msgj_kernel(const f16* __restrict__ Qz, const f16* __restrict__ U,
                            const f16* __restrict__ Vt, const int* __restrict__ mask,
                            const float* __restrict__ rowLinv, f16* __restrict__ Macc) {
    int jt = blockIdx.x, h = blockIdx.y, n = blockIdx.z;
    int t = threadIdx.x;
    int w = t >> 6, l = t & 63, m = l & 15, q = l >> 4;

    __shared__ __align__(16) f16 Qs[64 * WPAD];
    __shared__ __align__(16) f16 Vb[128 * UBPAD];
    __shared__ __align__(16) f16 Pb[64 * PBPAD];

    size_t hoff = (size_t)(n * Hn + h);

    // stage U j-tile, read jt-invariant A-fragments
    {
        const f16* src = U + (hoff * Ln + jt * 64) * Dn;
        #pragma unroll
        for (int ii = 0; ii < 4; ii++) {
            int idx = t + 256 * ii; int r = idx >> 4, c = idx & 15;
            *(float4*)&Qs[r * WPAD + c * 8] = *(const float4*)(src + (size_t)r * Dn + c * 8);
        }
    }
    __syncthreads();
    half8 au[4];
    #pragma unroll
    for (int ks = 0; ks < 4; ks++)
        au[ks] = *(const half8*)&Qs[(w * 16 + m) * WPAD + ks * 32 + q * 8];
    int jm[4];
    #pragma unroll
    for (int reg = 0; reg < 4; reg++)
        jm[reg] = mask[n * Ln + jt * 64 + w * 16 + 4 * q + reg];

    // prefetch it2=0
    float4 pQ[4], pV[4];
    float plv[4];
    {
        const f16* qsrc = Qz + (size_t)n * Ln * Dn;
        const f16* vsrc = Vt + hoff * Dn * Ln;
        #pragma unroll
        for (int ii = 0; ii < 4; ii++) {
            int idx = t + 256 * ii;
            pQ[ii] = *(const float4*)(qsrc + (size_t)(idx >> 4) * Dn + (idx & 15) * 8);
            pV[ii] = *(const float4*)(vsrc + (size_t)(idx >> 3) * Ln + (idx & 7) * 8);
        }
        #pragma unroll
        for (int ct = 0; ct < 4; ct++)
            plv[ct] = rowLinv[hoff * Ln + ct * 16 + m];
    }
    __syncthreads();  // au reads complete before Qs is overwritten

    floatx4 Oacc[8];
    #pragma unroll
    for (int c = 0; c < 8; c++) Oacc[c] = (floatx4){0.f, 0.f, 0.f, 0.f};
    f16* Pw = &Pb[w * 16 * PBPAD];

    for (int it2 = 0; it2 < 16; it2++) {
        #pragma unroll
        for (int ii = 0; ii < 4; ii++) {
            int idx = t + 256 * ii;
            *(float4*)&Qs[(idx >> 4) * WPAD + (idx & 15) * 8] = pQ[ii];
            *(float4*)&Vb[(idx >> 3) * UBPAD + (idx & 7) * 8] = pV[ii];
        }
        float lv[4];
        #pragma unroll
        for (int ct = 0; ct < 4; ct++) lv[ct] = plv[ct];
        __syncthreads();
        if (it2 < 15) {
            const f16* qsrc = Qz + ((size_t)n * Ln + (it2 + 1) * 64) * Dn;
            const f16* vsrc = Vt + hoff * Dn * Ln + (it2 + 1) * 64;
            #pragma unroll
            for (int ii = 0; ii < 4; ii++) {
                int idx = t + 256 * ii;
                pQ[ii] = *(const float4*)(qsrc + (size_t)(idx >> 4) * Dn + (idx & 15) * 8);
                pV[ii] = *(const float4*)(vsrc + (size_t)(idx >> 3) * Ln + (idx & 7) * 8);
            }
            #pragma unroll
            for (int ct = 0; ct < 4; ct++)
                plv[ct] = rowLinv[hoff * Ln + (it2 + 1) * 64 + ct * 16 + m];
        }
        // S^T[j = 16w+4q+reg][i = ct*16+m]; p = exp(s) * rowLinv[i] * jm[j]
        #pragma unroll
        for (int ct = 0; ct < 4; ct++) {
            floatx4 s = {0.f, 0.f, 0.f, 0.f};
            #pragma unroll
            for (int ks = 0; ks < 4; ks++) {
                half8 b = *(const half8*)&Qs[(ct * 16 + m) * WPAD + ks * 32 + q * 8];
                s = MFMA(au[ks], b, s);
            }
            #pragma unroll
            for (int reg = 0; reg < 4; reg++) {
                float p = jm[reg] ? __expf(fminf(s[reg], 11.f)) * lv[ct] : 0.f;
                Pw[(4 * q + reg) * PBPAD + ct * 16 + m] = (f16)p;
            }
        }
        // O[strip j rows][128 cols] += P^T-strip * V_tile
        #pragma unroll
        for (int ks2 = 0; ks2 < 2; ks2++) {
            half8 aP = *(const half8*)&Pw[m * PBPAD + ks2 * 32 + q * 8];
            #pragma unroll
            for (int c = 0; c < 8; c++) {
                half8 bV = *(const half8*)&Vb[(c * 16 + m) * UBPAD + ks2 * 32 + q * 8];
                Oacc[c] = MFMA(aP, bV, Oacc[c]);
            }
        }
        __syncthreads();
    }

    f16* Mo = Macc + (hoff * Ln + (size_t)jt * 64 + w * 16 + 4 * q) * Dn;
    #pragma unroll
    for (int reg = 0; reg < 4; reg++)
        #pragma unroll
        for (int c = 0; c < 8; c++) {
            f16* p = &Mo[(size_t)reg * Dn + c * 16 + m];
            *p = (f16)((float)*p + Oacc[c][reg]);
        }
}

// ---------------- fused combine (+softmax | +mask) --------------------------
__global__ void combine_kernel(const float* __restrict__ x, const f16* __restrict__ Macc,
                               const int* __restrict__ mask, float* __restrict__ out,
                               f16* __restrict__ Qzh, int do_softmax, int do_mask) {
    int row = blockIdx.x;           // B*L rows
    int t = threadIdx.x;            // 0..127
    __shared__ float red[2];
    int n = row >> 10;
    float acc = x[(size_t)row * Dn + t];
    const f16* mp = Macc + (size_t)n * Hn * Ln * Dn + (size_t)(row & 1023) * Dn + t;
    #pragma unroll
    for (int h = 0; h < Hn; h++) acc += (float)mp[(size_t)h * Ln * Dn];
    float o = acc;
    if (do_mask && mask[row] == 0) o = 0.f;
    out[(size_t)row * Dn + t] = o;
    if (do_softmax) {
        float m = acc;
        #pragma unroll
        for (int off = 1; off < 64; off <<= 1) m = fmaxf(m, __shfl_xor(m, off, 64));
        if ((t & 63) == 0) red[t >> 6] = m;
        __syncthreads();
        m = fmaxf(red[0], red[1]);
        float e = __expf(acc - m);
        float s = e;
        #pragma unroll
        for (int off = 1; off < 64; off <<= 1) s += __shfl_xor(s, off, 64);
        __syncthreads();
        if ((t & 63) == 0) red[t >> 6] = s;
        __syncthreads();
        s = red[0] + red[1];
        Qzh[(size_t)row * Dn + t] = (f16)(e / s);
    }
}

extern "C" void kernel_launch(void* const* d_in, const int* in_sizes, int n_in,
                              void* d_out, int out_size, void* d_ws, size_t ws_size,
                              hipStream_t stream) {
    const float* x       = (const float*)d_in[0];
    const int*   mask    = (const int*)d_in[1];
    const float* ternary = (const float*)d_in[2];
    const float* global_ = (const float*)d_in[3];
    float* out = (float*)d_out;
    (void)ws_size; (void)n_in; (void)in_sizes; (void)out_size;

    char* ws = (char*)d_ws;
    size_t o = 0;
    f16* Qzh = (f16*)(ws + o); o += (size_t)Bn * Ln * Dn * 2;
    f16* U   = (f16*)(ws + o); o += (size_t)Bn * Hn * Ln * Dn * 2;
    f16* Ut  = (f16*)(ws + o); o += (size_t)Bn * Hn * Ln * Dn * 2;
    f16* Vt  = (f16*)(ws + o); o += (size_t)Bn * Hn * Ln * Dn * 2;
    f16* TpA = (f16*)(ws + o); o += (size_t)Hn * Dn * Dn * 2;
    f16* TpB = (f16*)(ws + o); o += (size_t)Hn * Dn * Dn * 2;
    f16* GpA = (f16*)(ws + o); o += (size_t)Hn * Gn * Dn * 2;
    f16* Gpt = (f16*)(ws + o); o += (size_t)Hn * Dn * Gn * 2;
    float* rowLinv = (float*)(ws + o); o += (size_t)Bn * Hn * Ln * 4;
    f16* Macc = (f16*)(ws + o); o += (size_t)Bn * Hn * Ln * Dn * 2;

    repack_kernel<<<(Dn * Dn * Hn + 255) / 256, 256, 0, stream>>>(ternary, global_, TpA, TpB, GpA, Gpt);
    softmax_rows_kernel<<<Bn * Ln, 128, 0, stream>>>(x, Qzh);

    for (int it = 0; it < NITERS; it++) {
        uv_kernel<<<dim3(Ln / 64, Hn, Bn), 256, 0, stream>>>(Qzh, TpA, TpB, U, Ut, Vt);
        msgi_kernel<<<dim3(Ln / 64, Hn, Bn), 256, 0, stream>>>(Qzh, U, Ut, GpA, Gpt, mask, Macc, rowLinv);
        msgj_kernel<<<dim3(Ln / 64, Hn, Bn), 256, 0, stream>>>(Qzh, U, Vt, mask, rowLinv, Macc);
        combine_kernel<<<Bn * Ln, 128, 0, stream>>>(x, Macc, mask, out, Qzh,
                                                    (it < NITERS - 1) ? 1 : 0,
                                                    (it == NITERS - 1) ? 1 : 0);
    }
}

// Round 5
// 434.412 us; speedup vs baseline: 2.2309x; 2.0199x over previous
//
#include <hip/hip_runtime.h>
#include <math.h>

#define Bn 4
#define Ln 1024
#define Dn 128
#define Hn 8
#define Gn 64
#define NITERS 4

typedef _Float16 f16;
typedef _Float16 half8 __attribute__((ext_vector_type(8)));
typedef _Float16 half4v __attribute__((ext_vector_type(4)));
typedef float floatx4 __attribute__((ext_vector_type(4)));

#define WPAD 136   // f16 stride, 128-col row-major tiles (group rotate: conflict-free)
#define UBPAD 72   // f16 stride, transposed 128x64 tiles
#define PPAD 72    // f16 stride, P tile [i][j] / [j][i]

#define MFMA(a, b, c) __builtin_amdgcn_mfma_f32_16x16x32_f16((a), (b), (c), 0, 0, 0)

// ---------------- repack ternary/global into f16 per-head layouts -----------
__global__ void repack_kernel(const float* __restrict__ ter, const float* __restrict__ glb,
                              f16* __restrict__ TpA, f16* __restrict__ TpB,
                              f16* __restrict__ GpA, f16* __restrict__ Gpt) {
    int idx = blockIdx.x * 256 + threadIdx.x;
    if (idx < Dn * Dn * Hn) {
        int h = idx % Hn; int b = (idx / Hn) % Dn; int a = idx / (Hn * Dn);
        f16 v = (f16)ter[idx];
        TpA[((size_t)h * Dn + a) * Dn + b] = v;
        TpB[((size_t)h * Dn + b) * Dn + a] = v;
    }
    if (idx < Gn * Dn * Hn) {
        int h = idx % Hn; int a = (idx / Hn) % Dn; int g = idx / (Hn * Dn);
        f16 v = (f16)glb[idx];
        GpA[((size_t)h * Gn + g) * Dn + a] = v;
        Gpt[((size_t)h * Dn + a) * Gn + g] = v;
    }
}

// ---------------- row softmax over D=128 (fp32 in, f16 out) -----------------
__global__ void softmax_rows_kernel(const float* __restrict__ in, f16* __restrict__ out) {
    int row = blockIdx.x;
    int t = threadIdx.x;  // 0..127
    __shared__ float red[2];
    float v = in[(size_t)row * Dn + t];
    float m = v;
    #pragma unroll
    for (int off = 1; off < 64; off <<= 1) m = fmaxf(m, __shfl_xor(m, off, 64));
    if ((t & 63) == 0) red[t >> 6] = m;
    __syncthreads();
    m = fmaxf(red[0], red[1]);
    float e = __expf(v - m);
    float s = e;
    #pragma unroll
    for (int off = 1; off < 64; off <<= 1) s += __shfl_xor(s, off, 64);
    __syncthreads();
    if ((t & 63) == 0) red[t >> 6] = s;
    __syncthreads();
    s = red[0] + red[1];
    out[(size_t)row * Dn + t] = (f16)(e / s);
}

// ---------------- U/V projection via MFMA (R2 structure, known-good) --------
__launch_bounds__(256, 4)
__global__ void uv_kernel(const f16* __restrict__ Qz, const f16* __restrict__ TpA,
                          const f16* __restrict__ TpB,
                          f16* __restrict__ U, f16* __restrict__ Ut, f16* __restrict__ Vt) {
    int bx = blockIdx.x;  // 16 j-strips of 64
    int h  = blockIdx.y;
    int n  = blockIdx.z;
    int t  = threadIdx.x;
    int w = t >> 6, l = t & 63, m = l & 15, q = l >> 4;

    __shared__ __align__(16) f16 Ts[128 * WPAD];

    int jrow = bx * 64 + w * 16 + m;
    const f16* qbase = Qz + ((size_t)n * Ln + jrow) * Dn;
    half8 aq[4];
    #pragma unroll
    for (int ks = 0; ks < 4; ks++)
        aq[ks] = *(const half8*)(qbase + ks * 32 + q * 8);

    size_t hoff = (size_t)(n * Hn + h);
    int jr0 = bx * 64 + w * 16 + 4 * q;

    // ---- pass 1: U = Qz * TpA^T ----
    {
        const f16* src = TpA + (size_t)h * Dn * Dn;
        for (int ii = 0; ii < 8; ii++) {
            int idx = t + 256 * ii; int r = idx >> 4, c = idx & 15;
            *(float4*)&Ts[r * WPAD + c * 8] = *(const float4*)(src + (size_t)r * Dn + c * 8);
        }
        __syncthreads();
        #pragma unroll
        for (int ct = 0; ct < 8; ct++) {
            floatx4 acc = {0.f, 0.f, 0.f, 0.f};
            #pragma unroll
            for (int ks = 0; ks < 4; ks++) {
                half8 b = *(const half8*)&Ts[(ct * 16 + m) * WPAD + ks * 32 + q * 8];
                acc = MFMA(aq[ks], b, acc);
            }
            f16* ub = U + (hoff * Ln + jr0) * Dn + ct * 16 + m;
            #pragma unroll
            for (int reg = 0; reg < 4; reg++) ub[(size_t)reg * Dn] = (f16)acc[reg];
            half4v pk = { (f16)acc[0], (f16)acc[1], (f16)acc[2], (f16)acc[3] };
            *(half4v*)(Ut + (hoff * Dn + ct * 16 + m) * Ln + jr0) = pk;
        }
        __syncthreads();
    }
    // ---- pass 2: V = Qz * TpB^T, stored transposed ----
    {
        const f16* src = TpB + (size_t)h * Dn * Dn;
        for (int ii = 0; ii < 8; ii++) {
            int idx = t + 256 * ii; int r = idx >> 4, c = idx & 15;
            *(float4*)&Ts[r * WPAD + c * 8] = *(const float4*)(src + (size_t)r * Dn + c * 8);
        }
        __syncthreads();
        #pragma unroll
        for (int ct = 0; ct < 8; ct++) {
            floatx4 acc = {0.f, 0.f, 0.f, 0.f};
            #pragma unroll
            for (int ks = 0; ks < 4; ks++) {
                half8 b = *(const half8*)&Ts[(ct * 16 + m) * WPAD + ks * 32 + q * 8];
                acc = MFMA(aq[ks], b, acc);
            }
            half4v pk = { (f16)acc[0], (f16)acc[1], (f16)acc[2], (f16)acc[3] };
            *(half4v*)(Vt + (hoff * Dn + ct * 16 + m) * Ln + jr0) = pk;
        }
    }
}

// ---------------- msg_i + msg_g: transposed scores, resident Qz B-frags -----
// Scores computed as S^T (rows j, cols i): A = U j-rows (from LDS per jt),
// B = Qz i-rows (resident VGPRs). P stored [i][j] via half4v writes; PV reads
// b128 A-frags. 2x2 wave quadrants. No prefetch arrays (scratch-spill trap).
__launch_bounds__(256, 3)
__global__ void msgi_kernel(const f16* __restrict__ Qz, const f16* __restrict__ U,
                            const f16* __restrict__ Ut, const f16* __restrict__ GpA,
                            const f16* __restrict__ Gpt, const int* __restrict__ mask,
                            f16* __restrict__ Macc, float* __restrict__ rowLinv) {
    int it = blockIdx.x, h = blockIdx.y, n = blockIdx.z;
    int t = threadIdx.x;
    int w = t >> 6, l = t & 63, m = l & 15, q = l >> 4;
    int rh = w >> 1, ch = w & 1;   // scores: j-half (rows), i-half (cols)
    int ih = w >> 1, ah = w & 1;   // PV: i-half (rows), a-half (cols)

    __shared__ __align__(16) f16 Us[64 * WPAD];    // U j-tile, row-major
    __shared__ __align__(16) f16 Ub[128 * UBPAD];  // Ut slice [a][j]
    __shared__ __align__(16) f16 Ps[64 * PPAD];    // P[i][j]
    __shared__ int jms[64];
    __shared__ float lpart[2][64];
    __shared__ float linvS[64];

    // resident B-frags: Qz rows of this i-tile (jt-invariant, 32 VGPRs)
    half8 bq[2][4];
    #pragma unroll
    for (int ib = 0; ib < 2; ib++) {
        const f16* qr = Qz + ((size_t)n * Ln + it * 64 + ch * 32 + ib * 16 + m) * Dn;
        #pragma unroll
        for (int ks = 0; ks < 4; ks++)
            bq[ib][ks] = *(const half8*)(qr + ks * 32 + q * 8);
    }
    int im[2];
    #pragma unroll
    for (int ib = 0; ib < 2; ib++)
        im[ib] = mask[n * Ln + it * 64 + ch * 32 + ib * 16 + m];

    float lacc[2] = {0.f, 0.f};
    floatx4 Oacc[2][4];
    #pragma unroll
    for (int ib = 0; ib < 2; ib++)
        #pragma unroll
        for (int at = 0; at < 4; at++) Oacc[ib][at] = (floatx4){0.f, 0.f, 0.f, 0.f};

    size_t hoff = (size_t)(n * Hn + h);

    for (int jt = 0; jt < 17; jt++) {
        int isg = (jt == 16);
        const f16* us; const f16* ub; int ustr;
        if (!isg) {
            us = U + (hoff * Ln + (size_t)jt * 64) * Dn;
            ub = Ut + hoff * Dn * Ln + jt * 64;
            ustr = Ln;
        } else {
            us = GpA + (size_t)h * Gn * Dn;
            ub = Gpt + (size_t)h * Dn * Gn;
            ustr = Gn;
        }
        __syncthreads();  // prior PV done with Ub/Ps
        // stage (load -> ds_write in place, R2 pattern: no long-lived regs)
        #pragma unroll
        for (int ii = 0; ii < 4; ii++) {
            int idx = t + 256 * ii;
            float4 v = *(const float4*)(us + (size_t)(idx >> 4) * Dn + (idx & 15) * 8);
            *(float4*)&Us[(idx >> 4) * WPAD + (idx & 15) * 8] = v;
            float4 v2 = *(const float4*)(ub + (size_t)(idx >> 3) * ustr + (idx & 7) * 8);
            *(float4*)&Ub[(idx >> 3) * UBPAD + (idx & 7) * 8] = v2;
        }
        if (t < 64) jms[t] = isg ? 1 : mask[n * Ln + jt * 64 + t];
        __syncthreads();

        // scores S^T[j][i]; write P[i][j] as half4v
        #pragma unroll
        for (int jb = 0; jb < 2; jb++) {
            half8 au[4];
            #pragma unroll
            for (int ks = 0; ks < 4; ks++)
                au[ks] = *(const half8*)&Us[(rh * 32 + jb * 16 + m) * WPAD + ks * 32 + q * 8];
            int jmr[4];
            #pragma unroll
            for (int reg = 0; reg < 4; reg++)
                jmr[reg] = jms[rh * 32 + jb * 16 + 4 * q + reg];
            #pragma unroll
            for (int ib = 0; ib < 2; ib++) {
                floatx4 s = {0.f, 0.f, 0.f, 0.f};
                #pragma unroll
                for (int ks = 0; ks < 4; ks++) s = MFMA(au[ks], bq[ib][ks], s);
                half4v pk;
                #pragma unroll
                for (int reg = 0; reg < 4; reg++) {
                    float p = (isg || (im[ib] && jmr[reg])) ? __expf(fminf(s[reg], 11.f)) : 0.f;
                    lacc[ib] += p;
                    pk[reg] = (f16)p;
                }
                *(half4v*)&Ps[(ch * 32 + ib * 16 + m) * PPAD + rh * 32 + jb * 16 + 4 * q] = pk;
            }
        }
        __syncthreads();

        // PV: O[i][a] += P[i][j] * U[j][a]; A = Ps rows (b128), B = Ub rows
        #pragma unroll
        for (int kst = 0; kst < 2; kst++) {
            half8 aP[2];
            #pragma unroll
            for (int ib = 0; ib < 2; ib++)
                aP[ib] = *(const half8*)&Ps[(ih * 32 + ib * 16 + m) * PPAD + kst * 32 + q * 8];
            #pragma unroll
            for (int at = 0; at < 4; at++) {
                half8 bU = *(const half8*)&Ub[(ah * 64 + at * 16 + m) * UBPAD + kst * 32 + q * 8];
                #pragma unroll
                for (int ib = 0; ib < 2; ib++)
                    Oacc[ib][at] = MFMA(aP[ib], bU, Oacc[ib][at]);
            }
        }
    }

    // epilogue: row sums (cols i live on m-lanes; sum over q then across rh)
    #pragma unroll
    for (int ib = 0; ib < 2; ib++) {
        float v = lacc[ib];
        v += __shfl_xor(v, 16, 64);
        v += __shfl_xor(v, 32, 64);
        lacc[ib] = v;
    }
    if (q == 0) {
        lpart[rh][ch * 32 + m] = lacc[0];
        lpart[rh][ch * 32 + 16 + m] = lacc[1];
    }
    __syncthreads();
    size_t rbase = hoff * Ln + (size_t)it * 64;
    if (t < 64) {
        float inv = 1.0f / (lpart[0][t] + lpart[1][t]);
        linvS[t] = inv;
        int mk = mask[n * Ln + it * 64 + t];
        rowLinv[rbase + t] = mk ? inv : 0.f;  // i-mask folded for msgj
    }
    __syncthreads();
    f16* Mo = Macc + rbase * Dn;
    #pragma unroll
    for (int ib = 0; ib < 2; ib++)
        #pragma unroll
        for (int reg = 0; reg < 4; reg++) {
            int row = ih * 32 + ib * 16 + 4 * q + reg;
            float inv = linvS[row];
            #pragma unroll
            for (int at = 0; at < 4; at++)
                Mo[(size_t)row * Dn + ah * 64 + at * 16 + m] = (f16)(Oacc[ib][at][reg] * inv);
        }
}

// ---------------- msg_j: mirrored structure, resident U B-frags -------------
__launch_bounds__(256, 3)
__global__ void msgj_kernel(const f16* __restrict__ Qz, const f16* __restrict__ U,
                            const f16* __restrict__ Vt, const int* __restrict__ mask,
                            const float* __restrict__ rowLinv, f16* __restrict__ Macc) {
    int jt = blockIdx.x, h = blockIdx.y, n = blockIdx.z;
    int t = threadIdx.x;
    int w = t >> 6, l = t & 63, m = l & 15, q = l >> 4;
    int ihs = w >> 1, jhs = w & 1;  // scores: i-half (rows), j-half (cols)
    int jh2 = w >> 1, bh = w & 1;   // PV: j-half (rows), b-half (cols)

    __shared__ __align__(16) f16 Qs[64 * WPAD];    // Qz i-tile, row-major
    __shared__ __align__(16) f16 Vb[128 * UBPAD];  // Vt slice [b][i]
    __shared__ __align__(16) f16 Psj[64 * PPAD];   // P'[j][i]
    __shared__ float lvS[64];

    size_t hoff = (size_t)(n * Hn + h);

    // resident B-frags: U rows of this j-tile (it2-invariant)
    half8 bu[2][4];
    #pragma unroll
    for (int jb = 0; jb < 2; jb++) {
        const f16* ur = U + (hoff * Ln + (size_t)jt * 64 + jhs * 32 + jb * 16 + m) * Dn;
        #pragma unroll
        for (int ks = 0; ks < 4; ks++)
            bu[jb][ks] = *(const half8*)(ur + ks * 32 + q * 8);
    }
    int jm[2];
    #pragma unroll
    for (int jb = 0; jb < 2; jb++)
        jm[jb] = mask[n * Ln + jt * 64 + jhs * 32 + jb * 16 + m];

    floatx4 Oacc[2][4];
    #pragma unroll
    for (int jb = 0; jb < 2; jb++)
        #pragma unroll
        for (int bt = 0; bt < 4; bt++) Oacc[jb][bt] = (floatx4){0.f, 0.f, 0.f, 0.f};

    for (int it2 = 0; it2 < 16; it2++) {
        const f16* qs = Qz + ((size_t)n * Ln + it2 * 64) * Dn;
        const f16* vs = Vt + hoff * Dn * Ln + it2 * 64;
        __syncthreads();  // prior PV done with Vb/Psj
        #pragma unroll
        for (int ii = 0; ii < 4; ii++) {
            int idx = t + 256 * ii;
            float4 v = *(const float4*)(qs + (size_t)(idx >> 4) * Dn + (idx & 15) * 8);
            *(float4*)&Qs[(idx >> 4) * WPAD + (idx & 15) * 8] = v;
            float4 v2 = *(const float4*)(vs + (size_t)(idx >> 3) * Ln + (idx & 7) * 8);
            *(float4*)&Vb[(idx >> 3) * UBPAD + (idx & 7) * 8] = v2;
        }
        if (t < 64) lvS[t] = rowLinv[hoff * Ln + it2 * 64 + t];
        __syncthreads();

        // scores S[i][j]; write P'[j][i] = exp(s)*linv_i*maskj as half4v
        #pragma unroll
        for (int ib = 0; ib < 2; ib++) {
            half8 aq2[4];
            #pragma unroll
            for (int ks = 0; ks < 4; ks++)
                aq2[ks] = *(const half8*)&Qs[(ihs * 32 + ib * 16 + m) * WPAD + ks * 32 + q * 8];
            float lv[4];
            #pragma unroll
            for (int reg = 0; reg < 4; reg++)
                lv[reg] = lvS[ihs * 32 + ib * 16 + 4 * q + reg];
            #pragma unroll
            for (int jb = 0; jb < 2; jb++) {
                floatx4 s = {0.f, 0.f, 0.f, 0.f};
                #pragma unroll
                for (int ks = 0; ks < 4; ks++) s = MFMA(aq2[ks], bu[jb][ks], s);
                half4v pk;
                #pragma unroll
                for (int reg = 0; reg < 4; reg++) {
                    float p = jm[jb] ? __expf(fminf(s[reg], 11.f)) * lv[reg] : 0.f;
                    pk[reg] = (f16)p;
                }
                *(half4v*)&Psj[(jhs * 32 + jb * 16 + m) * PPAD + ihs * 32 + ib * 16 + 4 * q] = pk;
            }
        }
        __syncthreads();

        // PV: O[j][b] += P'[j][i] * V[i][b]; A = Psj rows, B = Vb rows
        #pragma unroll
        for (int kst = 0; kst < 2; kst++) {
            half8 aP[2];
            #pragma unroll
            for (int jb = 0; jb < 2; jb++)
                aP[jb] = *(const half8*)&Psj[(jh2 * 32 + jb * 16 + m) * PPAD + kst * 32 + q * 8];
            #pragma unroll
            for (int bt = 0; bt < 4; bt++) {
                half8 bV = *(const half8*)&Vb[(bh * 64 + bt * 16 + m) * UBPAD + kst * 32 + q * 8];
                #pragma unroll
                for (int jb = 0; jb < 2; jb++)
                    Oacc[jb][bt] = MFMA(aP[jb], bV, Oacc[jb][bt]);
            }
        }
    }

    f16* Mo = Macc + (hoff * Ln + (size_t)jt * 64) * Dn;
    #pragma unroll
    for (int jb = 0; jb < 2; jb++)
        #pragma unroll
        for (int reg = 0; reg < 4; reg++) {
            int row = jh2 * 32 + jb * 16 + 4 * q + reg;
            #pragma unroll
            for (int bt = 0; bt < 4; bt++) {
                f16* p = &Mo[(size_t)row * Dn + bh * 64 + bt * 16 + m];
                *p = (f16)((float)*p + Oacc[jb][bt][reg]);
            }
        }
}

// ---------------- fused combine (+softmax | +mask) --------------------------
__global__ void combine_kernel(const float* __restrict__ x, const f16* __restrict__ Macc,
                               const int* __restrict__ mask, float* __restrict__ out,
                               f16* __restrict__ Qzh, int do_softmax, int do_mask) {
    int row = blockIdx.x;           // B*L rows
    int t = threadIdx.x;            // 0..127
    __shared__ float red[2];
    int n = row >> 10;
    float acc = x[(size_t)row * Dn + t];
    const f16* mp = Macc + (size_t)n * Hn * Ln * Dn + (size_t)(row & 1023) * Dn + t;
    #pragma unroll
    for (int h = 0; h < Hn; h++) acc += (float)mp[(size_t)h * Ln * Dn];
    float o = acc;
    if (do_mask && mask[row] == 0) o = 0.f;
    out[(size_t)row * Dn + t] = o;
    if (do_softmax) {
        float m = acc;
        #pragma unroll
        for (int off = 1; off < 64; off <<= 1) m = fmaxf(m, __shfl_xor(m, off, 64));
        if ((t & 63) == 0) red[t >> 6] = m;
        __syncthreads();
        m = fmaxf(red[0], red[1]);
        float e = __expf(acc - m);
        float s = e;
        #pragma unroll
        for (int off = 1; off < 64; off <<= 1) s += __shfl_xor(s, off, 64);
        __syncthreads();
        if ((t & 63) == 0) red[t >> 6] = s;
        __syncthreads();
        s = red[0] + red[1];
        Qzh[(size_t)row * Dn + t] = (f16)(e / s);
    }
}

extern "C" void kernel_launch(void* const* d_in, const int* in_sizes, int n_in,
                              void* d_out, int out_size, void* d_ws, size_t ws_size,
                              hipStream_t stream) {
    const float* x       = (const float*)d_in[0];
    const int*   mask    = (const int*)d_in[1];
    const float* ternary = (const float*)d_in[2];
    const float* global_ = (const float*)d_in[3];
    float* out = (float*)d_out;
    (void)ws_size; (void)n_in; (void)in_sizes; (void)out_size;

    char* ws = (char*)d_ws;
    size_t o = 0;
    f16* Qzh = (f16*)(ws + o); o += (size_t)Bn * Ln * Dn * 2;
    f16* U   = (f16*)(ws + o); o += (size_t)Bn * Hn * Ln * Dn * 2;
    f16* Ut  = (f16*)(ws + o); o += (size_t)Bn * Hn * Ln * Dn * 2;
    f16* Vt  = (f16*)(ws + o); o += (size_t)Bn * Hn * Ln * Dn * 2;
    f16* TpA = (f16*)(ws + o); o += (size_t)Hn * Dn * Dn * 2;
    f16* TpB = (f16*)(ws + o); o += (size_t)Hn * Dn * Dn * 2;
    f16* GpA = (f16*)(ws + o); o += (size_t)Hn * Gn * Dn * 2;
    f16* Gpt = (f16*)(ws + o); o += (size_t)Hn * Dn * Gn * 2;
    float* rowLinv = (float*)(ws + o); o += (size_t)Bn * Hn * Ln * 4;
    f16* Macc = (f16*)(ws + o); o += (size_t)Bn * Hn * Ln * Dn * 2;

    repack_kernel<<<(Dn * Dn * Hn + 255) / 256, 256, 0, stream>>>(ternary, global_, TpA, TpB, GpA, Gpt);
    softmax_rows_kernel<<<Bn * Ln, 128, 0, stream>>>(x, Qzh);

    for (int it = 0; it < NITERS; it++) {
        uv_kernel<<<dim3(Ln / 64, Hn, Bn), 256, 0, stream>>>(Qzh, TpA, TpB, U, Ut, Vt);
        msgi_kernel<<<dim3(Ln / 64, Hn, Bn), 256, 0, stream>>>(Qzh, U, Ut, GpA, Gpt, mask, Macc, rowLinv);
        msgj_kernel<<<dim3(Ln / 64, Hn, Bn), 256, 0, stream>>>(Qzh, U, Vt, mask, rowLinv, Macc);
        combine_kernel<<<Bn * Ln, 128, 0, stream>>>(x, Macc, mask, out, Qzh,
                                                    (it < NITERS - 1) ? 1 : 0,
                                                    (it == NITERS - 1) ? 1 : 0);
    }
}

// Round 7
// 395.116 us; speedup vs baseline: 2.4527x; 1.0995x over previous
//
#include <hip/hip_runtime.h>
#include <math.h>

#define Bn 4
#define Ln 1024
#define Dn 128
#define Hn 8
#define Gn 64
#define NITERS 4

typedef _Float16 f16;
typedef _Float16 half8 __attribute__((ext_vector_type(8)));
typedef _Float16 half4v __attribute__((ext_vector_type(4)));
typedef float floatx4 __attribute__((ext_vector_type(4)));

#define WPAD 136   // f16 stride for uv_kernel row-major tiles
#define PPAD 72    // f16 stride, P tile [i][j] / [j][i]

#define MFMA(a, b, c) __builtin_amdgcn_mfma_f32_16x16x32_f16((a), (b), (c), 0, 0, 0)

// async global->LDS, 16B per lane; dest = lds_base + lane*16 (wave-uniform base)
__device__ __forceinline__ void gl_lds16(const f16* g, f16* l) {
    __builtin_amdgcn_global_load_lds(
        (const __attribute__((address_space(1))) void*)(g),
        (__attribute__((address_space(3))) void*)(l),
        16, 0, 0);
}

// Issue one 64x128 tile (row stride Dn) into UsB and one 128x64 tile (row
// stride sb) into UbB, both XOR-swizzled: 16B-group g stored at g^(row&7).
// Per wave: 8 calls of 1KB. Inverse swizzle applied to the global address.
__device__ __forceinline__ void issue_tiles(const f16* us, const f16* ub, int sb,
                                            f16* UsB, f16* UbB, int w, int l) {
    #pragma unroll
    for (int k = 0; k < 4; k++) {
        int c = w * 4 + k;
        {   // Us: 64 rows x 16 groups
            int r = c * 4 + (l >> 4); int g = (l & 15) ^ (r & 7);
            gl_lds16(us + (size_t)r * Dn + g * 8, UsB + c * 512);
        }
        {   // Ub: 128 rows x 8 groups
            int r = c * 8 + (l >> 3); int g = (l & 7) ^ (r & 7);
            gl_lds16(ub + (size_t)r * sb + g * 8, UbB + c * 512);
        }
    }
}

// ---------------- repack ternary/global into f16 per-head layouts -----------
__global__ void repack_kernel(const float* __restrict__ ter, const float* __restrict__ glb,
                              f16* __restrict__ TpA, f16* __restrict__ TpB,
                              f16* __restrict__ GpA, f16* __restrict__ Gpt) {
    int idx = blockIdx.x * 256 + threadIdx.x;
    if (idx < Dn * Dn * Hn) {
        int h = idx % Hn; int b = (idx / Hn) % Dn; int a = idx / (Hn * Dn);
        f16 v = (f16)ter[idx];
        TpA[((size_t)h * Dn + a) * Dn + b] = v;
        TpB[((size_t)h * Dn + b) * Dn + a] = v;
    }
    if (idx < Gn * Dn * Hn) {
        int h = idx % Hn; int a = (idx / Hn) % Dn; int g = idx / (Hn * Dn);
        f16 v = (f16)glb[idx];
        GpA[((size_t)h * Gn + g) * Dn + a] = v;
        Gpt[((size_t)h * Dn + a) * Gn + g] = v;
    }
}

// ---------------- row softmax over D=128 (fp32 in, f16 out) -----------------
__global__ void softmax_rows_kernel(const float* __restrict__ in, f16* __restrict__ out) {
    int row = blockIdx.x;
    int t = threadIdx.x;  // 0..127
    __shared__ float red[2];
    float v = in[(size_t)row * Dn + t];
    float m = v;
    #pragma unroll
    for (int off = 1; off < 64; off <<= 1) m = fmaxf(m, __shfl_xor(m, off, 64));
    if ((t & 63) == 0) red[t >> 6] = m;
    __syncthreads();
    m = fmaxf(red[0], red[1]);
    float e = __expf(v - m);
    float s = e;
    #pragma unroll
    for (int off = 1; off < 64; off <<= 1) s += __shfl_xor(s, off, 64);
    __syncthreads();
    if ((t & 63) == 0) red[t >> 6] = s;
    __syncthreads();
    s = red[0] + red[1];
    out[(size_t)row * Dn + t] = (f16)(e / s);
}

// ---------------- U/V projection via MFMA (R2 structure, known-good) --------
__launch_bounds__(256, 4)
__global__ void uv_kernel(const f16* __restrict__ Qz, const f16* __restrict__ TpA,
                          const f16* __restrict__ TpB,
                          f16* __restrict__ U, f16* __restrict__ Ut, f16* __restrict__ Vt) {
    int bx = blockIdx.x;  // 16 j-strips of 64
    int h  = blockIdx.y;
    int n  = blockIdx.z;
    int t  = threadIdx.x;
    int w = t >> 6, l = t & 63, m = l & 15, q = l >> 4;

    __shared__ __align__(16) f16 Ts[128 * WPAD];

    int jrow = bx * 64 + w * 16 + m;
    const f16* qbase = Qz + ((size_t)n * Ln + jrow) * Dn;
    half8 aq[4];
    #pragma unroll
    for (int ks = 0; ks < 4; ks++)
        aq[ks] = *(const half8*)(qbase + ks * 32 + q * 8);

    size_t hoff = (size_t)(n * Hn + h);
    int jr0 = bx * 64 + w * 16 + 4 * q;

    // ---- pass 1: U = Qz * TpA^T ----
    {
        const f16* src = TpA + (size_t)h * Dn * Dn;
        for (int ii = 0; ii < 8; ii++) {
            int idx = t + 256 * ii; int r = idx >> 4, c = idx & 15;
            *(float4*)&Ts[r * WPAD + c * 8] = *(const float4*)(src + (size_t)r * Dn + c * 8);
        }
        __syncthreads();
        #pragma unroll
        for (int ct = 0; ct < 8; ct++) {
            floatx4 acc = {0.f, 0.f, 0.f, 0.f};
            #pragma unroll
            for (int ks = 0; ks < 4; ks++) {
                half8 b = *(const half8*)&Ts[(ct * 16 + m) * WPAD + ks * 32 + q * 8];
                acc = MFMA(aq[ks], b, acc);
            }
            f16* ub = U + (hoff * Ln + jr0) * Dn + ct * 16 + m;
            #pragma unroll
            for (int reg = 0; reg < 4; reg++) ub[(size_t)reg * Dn] = (f16)acc[reg];
            half4v pk = { (f16)acc[0], (f16)acc[1], (f16)acc[2], (f16)acc[3] };
            *(half4v*)(Ut + (hoff * Dn + ct * 16 + m) * Ln + jr0) = pk;
        }
        __syncthreads();
    }
    // ---- pass 2: V = Qz * TpB^T, stored transposed ----
    {
        const f16* src = TpB + (size_t)h * Dn * Dn;
        for (int ii = 0; ii < 8; ii++) {
            int idx = t + 256 * ii; int r = idx >> 4, c = idx & 15;
            *(float4*)&Ts[r * WPAD + c * 8] = *(const float4*)(src + (size_t)r * Dn + c * 8);
        }
        __syncthreads();
        #pragma unroll
        for (int ct = 0; ct < 8; ct++) {
            floatx4 acc = {0.f, 0.f, 0.f, 0.f};
            #pragma unroll
            for (int ks = 0; ks < 4; ks++) {
                half8 b = *(const half8*)&Ts[(ct * 16 + m) * WPAD + ks * 32 + q * 8];
                acc = MFMA(aq[ks], b, acc);
            }
            half4v pk = { (f16)acc[0], (f16)acc[1], (f16)acc[2], (f16)acc[3] };
            *(half4v*)(Vt + (hoff * Dn + ct * 16 + m) * Ln + jr0) = pk;
        }
    }
}

// ---------------- msg_i + msg_g: transposed scores + async double-buffer ----
// Scores S^T (A = U j-rows from LDS, B = resident Qz i-rows). Staging via
// global_load_lds width=16 into XOR-swizzled unpadded tiles, double-buffered:
// loads for jt+1 issued before the scores of jt. 2 barriers per jt.
__launch_bounds__(256, 2)
__global__ void msgi_kernel(const f16* __restrict__ Qz, const f16* __restrict__ U,
                            const f16* __restrict__ Ut, const f16* __restrict__ GpA,
                            const f16* __restrict__ Gpt, const int* __restrict__ mask,
                            f16* __restrict__ Macc, float* __restrict__ rowLinv) {
    int it = blockIdx.x, h = blockIdx.y, n = blockIdx.z;
    int t = threadIdx.x;
    int w = t >> 6, l = t & 63, m = l & 15, q = l >> 4;
    int rh = w >> 1, ch = w & 1;   // scores: j-half (rows), i-half (cols)
    int ih = w >> 1, ah = w & 1;   // PV: i-half (rows), a-half (cols)

    __shared__ __align__(16) f16 Us[2][64 * 128];    // U j-tile, swizzled
    __shared__ __align__(16) f16 Ub[2][128 * 64];    // Ut slice [a][j], swizzled
    __shared__ __align__(16) f16 Ps[64 * PPAD];      // P[i][j], padded
    __shared__ int jms[2][64];
    __shared__ float lpart[2][64];
    __shared__ float linvS[64];

    // resident B-frags: Qz rows of this i-tile (jt-invariant, 32 VGPRs)
    half8 bq[2][4];
    #pragma unroll
    for (int ib = 0; ib < 2; ib++) {
        const f16* qr = Qz + ((size_t)n * Ln + it * 64 + ch * 32 + ib * 16 + m) * Dn;
        #pragma unroll
        for (int ks = 0; ks < 4; ks++)
            bq[ib][ks] = *(const half8*)(qr + ks * 32 + q * 8);
    }
    int im[2];
    #pragma unroll
    for (int ib = 0; ib < 2; ib++)
        im[ib] = mask[n * Ln + it * 64 + ch * 32 + ib * 16 + m];

    float lacc[2] = {0.f, 0.f};
    floatx4 Oacc[2][4];
    #pragma unroll
    for (int ib = 0; ib < 2; ib++)
        #pragma unroll
        for (int at = 0; at < 4; at++) Oacc[ib][at] = (floatx4){0.f, 0.f, 0.f, 0.f};

    size_t hoff = (size_t)(n * Hn + h);

    // preload jt=0
    issue_tiles(U + hoff * Ln * Dn, Ut + hoff * Dn * Ln, Ln, Us[0], Ub[0], w, l);
    if (t < 64) jms[0][t] = mask[n * Ln + t];
    __syncthreads();  // drains DMA (vmcnt0 at barrier), jms visible

    for (int jt = 0; jt < 17; jt++) {
        int cur = jt & 1, nxt = cur ^ 1;
        // issue next tile into the free buffer (flies across the scores phase)
        if (jt + 1 < 17) {
            const f16 *us, *ub; int sb;
            if (jt + 1 < 16) {
                us = U + (hoff * Ln + (size_t)(jt + 1) * 64) * Dn;
                ub = Ut + hoff * Dn * Ln + (jt + 1) * 64;
                sb = Ln;
            } else {
                us = GpA + (size_t)h * Gn * Dn;
                ub = Gpt + (size_t)h * Dn * Gn;
                sb = Gn;
            }
            issue_tiles(us, ub, sb, Us[nxt], Ub[nxt], w, l);
            if (t < 64) jms[nxt][t] = (jt + 1 < 16) ? mask[n * Ln + (jt + 1) * 64 + t] : 1;
        }
        int isg = (jt == 16);
        // scores S^T[j][i] from Us[cur] (swizzled reads); write P[i][j]
        #pragma unroll
        for (int jb = 0; jb < 2; jb++) {
            int r0 = rh * 32 + jb * 16 + m;
            half8 au[4];
            #pragma unroll
            for (int ks = 0; ks < 4; ks++)
                au[ks] = *(const half8*)&Us[cur][((size_t)r0 << 7) + ((((ks << 2) + q)) ^ (r0 & 7)) * 8];
            int jmr[4];
            #pragma unroll
            for (int reg = 0; reg < 4; reg++)
                jmr[reg] = jms[cur][rh * 32 + jb * 16 + 4 * q + reg];
            #pragma unroll
            for (int ib = 0; ib < 2; ib++) {
                floatx4 s = {0.f, 0.f, 0.f, 0.f};
                #pragma unroll
                for (int ks = 0; ks < 4; ks++) s = MFMA(au[ks], bq[ib][ks], s);
                half4v pk;
                #pragma unroll
                for (int reg = 0; reg < 4; reg++) {
                    float p = (isg || (im[ib] && jmr[reg])) ? __expf(fminf(s[reg], 11.f)) : 0.f;
                    lacc[ib] += p;
                    pk[reg] = (f16)p;
                }
                *(half4v*)&Ps[(ch * 32 + ib * 16 + m) * PPAD + rh * 32 + jb * 16 + 4 * q] = pk;
            }
        }
        __syncthreads();  // P visible (also drains jt+1 DMA)

        // PV: O[i][a] += P[i][j] * U[j][a]; B-frags from swizzled Ub[cur]
        #pragma unroll
        for (int kst = 0; kst < 2; kst++) {
            half8 aP[2];
            #pragma unroll
            for (int ib = 0; ib < 2; ib++)
                aP[ib] = *(const half8*)&Ps[(ih * 32 + ib * 16 + m) * PPAD + kst * 32 + q * 8];
            #pragma unroll
            for (int at = 0; at < 4; at++) {
                int r0 = ah * 64 + at * 16 + m;
                half8 bU = *(const half8*)&Ub[cur][((size_t)r0 << 6) + ((((kst << 2) + q)) ^ (r0 & 7)) * 8];
                #pragma unroll
                for (int ib = 0; ib < 2; ib++)
                    Oacc[ib][at] = MFMA(aP[ib], bU, Oacc[ib][at]);
            }
        }
        __syncthreads();  // release cur buffers for jt+2 DMA
    }

    // epilogue: row sums (cols i live on m-lanes; sum over q then across rh)
    #pragma unroll
    for (int ib = 0; ib < 2; ib++) {
        float v = lacc[ib];
        v += __shfl_xor(v, 16, 64);
        v += __shfl_xor(v, 32, 64);
        lacc[ib] = v;
    }
    if (q == 0) {
        lpart[rh][ch * 32 + m] = lacc[0];
        lpart[rh][ch * 32 + 16 + m] = lacc[1];
    }
    __syncthreads();
    size_t rbase = hoff * Ln + (size_t)it * 64;
    if (t < 64) {
        float inv = 1.0f / (lpart[0][t] + lpart[1][t]);
        linvS[t] = inv;
        int mk = mask[n * Ln + it * 64 + t];
        rowLinv[rbase + t] = mk ? inv : 0.f;  // i-mask folded for msgj
    }
    __syncthreads();
    f16* Mo = Macc + rbase * Dn;
    #pragma unroll
    for (int ib = 0; ib < 2; ib++)
        #pragma unroll
        for (int reg = 0; reg < 4; reg++) {
            int row = ih * 32 + ib * 16 + 4 * q + reg;
            float inv = linvS[row];
            #pragma unroll
            for (int at = 0; at < 4; at++)
                Mo[(size_t)row * Dn + ah * 64 + at * 16 + m] = (f16)(Oacc[ib][at][reg] * inv);
        }
}

// ---------------- msg_j: mirrored, async double-buffer ----------------------
__launch_bounds__(256, 2)
__global__ void msgj_kernel(const f16* __restrict__ Qz, const f16* __restrict__ U,
                            const f16* __restrict__ Vt, const int* __restrict__ mask,
                            const float* __restrict__ rowLinv, f16* __restrict__ Macc) {
    int jt = blockIdx.x, h = blockIdx.y, n = blockIdx.z;
    int t = threadIdx.x;
    int w = t >> 6, l = t & 63, m = l & 15, q = l >> 4;
    int ihs = w >> 1, jhs = w & 1;  // scores: i-half (rows), j-half (cols)
    int jh2 = w >> 1, bh = w & 1;   // PV: j-half (rows), b-half (cols)

    __shared__ __align__(16) f16 Qs[2][64 * 128];   // Qz i-tile, swizzled
    __shared__ __align__(16) f16 Vb[2][128 * 64];   // Vt slice [b][i], swizzled
    __shared__ __align__(16) f16 Psj[64 * PPAD];    // P'[j][i], padded
    __shared__ float lvS[2][64];

    size_t hoff = (size_t)(n * Hn + h);

    // resident B-frags: U rows of this j-tile (it2-invariant)
    half8 bu[2][4];
    #pragma unroll
    for (int jb = 0; jb < 2; jb++) {
        const f16* ur = U + (hoff * Ln + (size_t)jt * 64 + jhs * 32 + jb * 16 + m) * Dn;
        #pragma unroll
        for (int ks = 0; ks < 4; ks++)
            bu[jb][ks] = *(const half8*)(ur + ks * 32 + q * 8);
    }
    int jm[2];
    #pragma unroll
    for (int jb = 0; jb < 2; jb++)
        jm[jb] = mask[n * Ln + jt * 64 + jhs * 32 + jb * 16 + m];

    floatx4 Oacc[2][4];
    #pragma unroll
    for (int jb = 0; jb < 2; jb++)
        #pragma unroll
        for (int bt = 0; bt < 4; bt++) Oacc[jb][bt] = (floatx4){0.f, 0.f, 0.f, 0.f};

    // preload it2=0
    issue_tiles(Qz + (size_t)n * Ln * Dn, Vt + hoff * Dn * Ln, Ln, Qs[0], Vb[0], w, l);
    if (t < 64) lvS[0][t] = rowLinv[hoff * Ln + t];
    __syncthreads();

    for (int it2 = 0; it2 < 16; it2++) {
        int cur = it2 & 1, nxt = cur ^ 1;
        if (it2 + 1 < 16) {
            issue_tiles(Qz + ((size_t)n * Ln + (size_t)(it2 + 1) * 64) * Dn,
                        Vt + hoff * Dn * Ln + (it2 + 1) * 64, Ln, Qs[nxt], Vb[nxt], w, l);
            if (t < 64) lvS[nxt][t] = rowLinv[hoff * Ln + (it2 + 1) * 64 + t];
        }
        // scores S[i][j] from Qs[cur]; write P'[j][i] = exp(s)*linv_i*maskj
        #pragma unroll
        for (int ib = 0; ib < 2; ib++) {
            int r0 = ihs * 32 + ib * 16 + m;
            half8 aq2[4];
            #pragma unroll
            for (int ks = 0; ks < 4; ks++)
                aq2[ks] = *(const half8*)&Qs[cur][((size_t)r0 << 7) + ((((ks << 2) + q)) ^ (r0 & 7)) * 8];
            float lv[4];
            #pragma unroll
            for (int reg = 0; reg < 4; reg++)
                lv[reg] = lvS[cur][ihs * 32 + ib * 16 + 4 * q + reg];
            #pragma unroll
            for (int jb = 0; jb < 2; jb++) {
                floatx4 s = {0.f, 0.f, 0.f, 0.f};
                #pragma unroll
                for (int ks = 0; ks < 4; ks++) s = MFMA(aq2[ks], bu[jb][ks], s);
                half4v pk;
                #pragma unroll
                for (int reg = 0; reg < 4; reg++) {
                    float p = jm[jb] ? __expf(fminf(s[reg], 11.f)) * lv[reg] : 0.f;
                    pk[reg] = (f16)p;
                }
                *(half4v*)&Psj[(jhs * 32 + jb * 16 + m) * PPAD + ihs * 32 + ib * 16 + 4 * q] = pk;
            }
        }
        __syncthreads();  // P' visible (drains next DMA too)

        // PV: O[j][b] += P'[j][i] * V[i][b]
        #pragma unroll
        for (int kst = 0; kst < 2; kst++) {
            half8 aP[2];
            #pragma unroll
            for (int jb = 0; jb < 2; jb++)
                aP[jb] = *(const half8*)&Psj[(jh2 * 32 + jb * 16 + m) * PPAD + kst * 32 + q * 8];
            #pragma unroll
            for (int bt = 0; bt < 4; bt++) {
                int r0 = bh * 64 + bt * 16 + m;
                half8 bV = *(const half8*)&Vb[cur][((size_t)r0 << 6) + ((((kst << 2) + q)) ^ (r0 & 7)) * 8];
                #pragma unroll
                for (int jb = 0; jb < 2; jb++)
                    Oacc[jb][bt] = MFMA(aP[jb], bV, Oacc[jb][bt]);
            }
        }
        __syncthreads();  // release cur buffers
    }

    f16* Mo = Macc + (hoff * Ln + (size_t)jt * 64) * Dn;
    #pragma unroll
    for (int jb = 0; jb < 2; jb++)
        #pragma unroll
        for (int reg = 0; reg < 4; reg++) {
            int row = jh2 * 32 + jb * 16 + 4 * q + reg;
            #pragma unroll
            for (int bt = 0; bt < 4; bt++) {
                f16* p = &Mo[(size_t)row * Dn + bh * 64 + bt * 16 + m];
                *p = (f16)((float)*p + Oacc[jb][bt][reg]);
            }
        }
}

// ---------------- fused combine (+softmax | +mask) --------------------------
__global__ void combine_kernel(const float* __restrict__ x, const f16* __restrict__ Macc,
                               const int* __restrict__ mask, float* __restrict__ out,
                               f16* __restrict__ Qzh, int do_softmax, int do_mask) {
    int row = blockIdx.x;           // B*L rows
    int t = threadIdx.x;            // 0..127
    __shared__ float red[2];
    int n = row >> 10;
    float acc = x[(size_t)row * Dn + t];
    const f16* mp = Macc + (size_t)n * Hn * Ln * Dn + (size_t)(row & 1023) * Dn + t;
    #pragma unroll
    for (int h = 0; h < Hn; h++) acc += (float)mp[(size_t)h * Ln * Dn];
    float o = acc;
    if (do_mask && mask[row] == 0) o = 0.f;
    out[(size_t)row * Dn + t] = o;
    if (do_softmax) {
        float m = acc;
        #pragma unroll
        for (int off = 1; off < 64; off <<= 1) m = fmaxf(m, __shfl_xor(m, off, 64));
        if ((t & 63) == 0) red[t >> 6] = m;
        __syncthreads();
        m = fmaxf(red[0], red[1]);
        float e = __expf(acc - m);
        float s = e;
        #pragma unroll
        for (int off = 1; off < 64; off <<= 1) s += __shfl_xor(s, off, 64);
        __syncthreads();
        if ((t & 63) == 0) red[t >> 6] = s;
        __syncthreads();
        s = red[0] + red[1];
        Qzh[(size_t)row * Dn + t] = (f16)(e / s);
    }
}

extern "C" void kernel_launch(void* const* d_in, const int* in_sizes, int n_in,
                              void* d_out, int out_size, void* d_ws, size_t ws_size,
                              hipStream_t stream) {
    const float* x       = (const float*)d_in[0];
    const int*   mask    = (const int*)d_in[1];
    const float* ternary = (const float*)d_in[2];
    const float* global_ = (const float*)d_in[3];
    float* out = (float*)d_out;
    (void)ws_size; (void)n_in; (void)in_sizes; (void)out_size;

    char* ws = (char*)d_ws;
    size_t o = 0;
    f16* Qzh = (f16*)(ws + o); o += (size_t)Bn * Ln * Dn * 2;
    f16* U   = (f16*)(ws + o); o += (size_t)Bn * Hn * Ln * Dn * 2;
    f16* Ut  = (f16*)(ws + o); o += (size_t)Bn * Hn * Ln * Dn * 2;
    f16* Vt  = (f16*)(ws + o); o += (size_t)Bn * Hn * Ln * Dn * 2;
    f16* TpA = (f16*)(ws + o); o += (size_t)Hn * Dn * Dn * 2;
    f16* TpB = (f16*)(ws + o); o += (size_t)Hn * Dn * Dn * 2;
    f16* GpA = (f16*)(ws + o); o += (size_t)Hn * Gn * Dn * 2;
    f16* Gpt = (f16*)(ws + o); o += (size_t)Hn * Dn * Gn * 2;
    float* rowLinv = (float*)(ws + o); o += (size_t)Bn * Hn * Ln * 4;
    f16* Macc = (f16*)(ws + o); o += (size_t)Bn * Hn * Ln * Dn * 2;

    repack_kernel<<<(Dn * Dn * Hn + 255) / 256, 256, 0, stream>>>(ternary, global_, TpA, TpB, GpA, Gpt);
    softmax_rows_kernel<<<Bn * Ln, 128, 0, stream>>>(x, Qzh);

    for (int it = 0; it < NITERS; it++) {
        uv_kernel<<<dim3(Ln / 64, Hn, Bn), 256, 0, stream>>>(Qzh, TpA, TpB, U, Ut, Vt);
        msgi_kernel<<<dim3(Ln / 64, Hn, Bn), 256, 0, stream>>>(Qzh, U, Ut, GpA, Gpt, mask, Macc, rowLinv);
        msgj_kernel<<<dim3(Ln / 64, Hn, Bn), 256, 0, stream>>>(Qzh, U, Vt, mask, rowLinv, Macc);
        combine_kernel<<<Bn * Ln, 128, 0, stream>>>(x, Macc, mask, out, Qzh,
                                                    (it < NITERS - 1) ? 1 : 0,
                                                    (it == NITERS - 1) ? 1 : 0);
    }
}